// Round 1
// baseline (10480.484 us; speedup 1.0000x reference)
//
#include <hip/hip_runtime.h>
#include <math.h>

#define B_ 512
#define N_ 20
#define H_ 450
#define L_ 56
#define V_ 780
#define T_ 38
#define NNODES (B_*N_)        // 10240
#define NEDGES (B_*2*(N_-1))  // 19456
#define NPROWS ((T_+1)*B_)    // 19968
#define K2H 900               // 2*H

#define BM 32
#define BN 32
#define BK 32

__device__ __forceinline__ float sigmoidf_(float v){ return 1.0f/(1.0f+expf(-v)); }

// x[i][:] = emb[wid[i]][:]
__global__ void k_gather_x(const float* __restrict__ emb, const int* __restrict__ wid,
                           float* __restrict__ x){
  int i = blockIdx.x; int w = wid[i];
  for (int j = threadIdx.x; j < H_; j += blockDim.x)
    x[(size_t)i*H_+j] = emb[(size_t)w*H_+j];
}

// Build per-step A matrices: A1=[sx|s], A2=[sx|arm], A3=[dx|(m_new later)]
__global__ void k_prep(const float* __restrict__ x, const float* __restrict__ m,
                       const float* __restrict__ rm,
                       const int* __restrict__ edge_src, const int* __restrict__ edge_dst,
                       const int* __restrict__ edge_pred, const int* __restrict__ step_eid,
                       int t, int P,
                       float* __restrict__ A1, float* __restrict__ A2, float* __restrict__ A3){
  int b = blockIdx.x;
  int eid = step_eid[t*B_ + b];
  int sn = edge_src[eid], dn = edge_dst[eid];
  for (int j = threadIdx.x; j < H_; j += blockDim.x){
    float sx = x[(size_t)sn*H_+j];
    A1[b*K2H+j] = sx; A2[b*K2H+j] = sx;
    A3[b*K2H+j] = x[(size_t)dn*H_+j];
    float s = 0.f, ar = 0.f;
    for (int p = 0; p < P; ++p){
      int e = edge_pred[eid*P+p];           // sentinel e==NEDGES -> zero row
      s  += m [(size_t)e*H_+j];
      ar += rm[(size_t)e*H_+j];
    }
    A1[b*K2H+H_+j] = s; A2[b*K2H+H_+j] = ar;
  }
}

// Dual GEMM: z=sigmoid(A1@Wz+bz), tc=tanh(A2@Wh+bh), m_new=(1-z)*s+z*tc -> A3[:,H_:]
__global__ __launch_bounds__(256) void k_gate(const float* __restrict__ A1,
    const float* __restrict__ A2, const float* __restrict__ Wz, const float* __restrict__ bz,
    const float* __restrict__ Wh, const float* __restrict__ bh, float* __restrict__ A3){
  __shared__ float As1[BM][BK+1], As2[BM][BK+1], Ws1[BK][BN+1], Ws2[BK][BN+1];
  int bx = blockIdx.x, by = blockIdx.y;
  int tx = threadIdx.x & 15, ty = threadIdx.x >> 4;
  float accZ[2][2] = {{0.f,0.f},{0.f,0.f}}, accH[2][2] = {{0.f,0.f},{0.f,0.f}};
  for (int kt = 0; kt < K2H; kt += BK){
    for (int l = threadIdx.x; l < BM*BK; l += 256){
      int r = l / BK, c = l % BK;
      int gr = by*BM + r, gk = kt + c;
      float a1 = 0.f, a2 = 0.f;
      if (gk < K2H){ a1 = A1[gr*K2H+gk]; a2 = A2[gr*K2H+gk]; }
      As1[r][c] = a1; As2[r][c] = a2;
    }
    for (int l = threadIdx.x; l < BK*BN; l += 256){
      int r = l / BN, c = l % BN;
      int gk = kt + r, gc = bx*BN + c;
      float w1 = 0.f, w2 = 0.f;
      if (gk < K2H && gc < H_){ w1 = Wz[gk*H_+gc]; w2 = Wh[gk*H_+gc]; }
      Ws1[r][c] = w1; Ws2[r][c] = w2;
    }
    __syncthreads();
    for (int kk = 0; kk < BK; ++kk){
      float a1a = As1[ty*2][kk],   a1b = As1[ty*2+1][kk];
      float a2a = As2[ty*2][kk],   a2b = As2[ty*2+1][kk];
      float w1a = Ws1[kk][tx*2],   w1b = Ws1[kk][tx*2+1];
      float w2a = Ws2[kk][tx*2],   w2b = Ws2[kk][tx*2+1];
      accZ[0][0] += a1a*w1a; accZ[0][1] += a1a*w1b;
      accZ[1][0] += a1b*w1a; accZ[1][1] += a1b*w1b;
      accH[0][0] += a2a*w2a; accH[0][1] += a2a*w2b;
      accH[1][0] += a2b*w2a; accH[1][1] += a2b*w2b;
    }
    __syncthreads();
  }
  for (int ii = 0; ii < 2; ++ii){
    int gr = by*BM + ty*2 + ii;
    for (int jj = 0; jj < 2; ++jj){
      int gc = bx*BN + tx*2 + jj;
      if (gc < H_){
        float z  = sigmoidf_(accZ[ii][jj] + bz[gc]);
        float tc = tanhf(accH[ii][jj] + bh[gc]);
        float s  = A1[gr*K2H + H_ + gc];
        A3[gr*K2H + H_ + gc] = (1.f - z)*s + z*tc;
      }
    }
  }
}

// r = sigmoid(A3 @ [Wr;Ur] + br); scatter m[eid]=m_new, rm[eid]=r*m_new
__global__ __launch_bounds__(256) void k_rgate(const float* __restrict__ A3,
    const float* __restrict__ Wr, const float* __restrict__ Ur, const float* __restrict__ br,
    const int* __restrict__ step_eid, int t, float* __restrict__ m, float* __restrict__ rm){
  __shared__ float As[BM][BK+1], Ws[BK][BN+1];
  int bx = blockIdx.x, by = blockIdx.y;
  int tx = threadIdx.x & 15, ty = threadIdx.x >> 4;
  float acc[2][2] = {{0.f,0.f},{0.f,0.f}};
  for (int kt = 0; kt < K2H; kt += BK){
    for (int l = threadIdx.x; l < BM*BK; l += 256){
      int r = l / BK, c = l % BK;
      int gr = by*BM + r, gk = kt + c;
      As[r][c] = (gk < K2H) ? A3[gr*K2H+gk] : 0.f;
    }
    for (int l = threadIdx.x; l < BK*BN; l += 256){
      int r = l / BN, c = l % BN;
      int gk = kt + r, gc = bx*BN + c;
      float w = 0.f;
      if (gk < K2H && gc < H_)
        w = (gk < H_) ? Wr[gk*H_+gc] : Ur[(gk-H_)*H_+gc];
      Ws[r][c] = w;
    }
    __syncthreads();
    for (int kk = 0; kk < BK; ++kk){
      float a0 = As[ty*2][kk], a1 = As[ty*2+1][kk];
      float w0 = Ws[kk][tx*2], w1 = Ws[kk][tx*2+1];
      acc[0][0] += a0*w0; acc[0][1] += a0*w1;
      acc[1][0] += a1*w0; acc[1][1] += a1*w1;
    }
    __syncthreads();
  }
  for (int ii = 0; ii < 2; ++ii){
    int gr = by*BM + ty*2 + ii;
    int eid = step_eid[t*B_ + gr];
    for (int jj = 0; jj < 2; ++jj){
      int gc = bx*BN + tx*2 + jj;
      if (gc < H_){
        float r_   = sigmoidf_(acc[ii][jj] + br[gc]);
        float mnew = A3[gr*K2H + H_ + gc];
        m [(size_t)eid*H_ + gc] = mnew;
        rm[(size_t)eid*H_ + gc] = r_*mnew;
      }
    }
  }
}

// h_steps[t][b][:] = sum over node_in[v] of m rows (after this step's scatter)
__global__ void k_hpull(const float* __restrict__ m, const int* __restrict__ node_in,
                        const int* __restrict__ step_v, int t, int Dn,
                        float* __restrict__ h_steps){
  int b = blockIdx.x;
  int v = step_v[t*B_+b];
  for (int j = threadIdx.x; j < H_; j += blockDim.x){
    float h = 0.f;
    for (int d = 0; d < Dn; ++d){
      int e = node_in[v*Dn+d];
      h += m[(size_t)e*H_+j];
    }
    h_steps[((size_t)t*B_+b)*H_ + j] = h;
  }
}

// Generic GEMM with virtual-A gather. mode 0: q_in rows; mode 1: p_in rows; mode 2: plain A.
__global__ __launch_bounds__(256) void k_mm(
    int rows, int cols, int K, int mode, int act,
    const float* __restrict__ Aplain, const float* __restrict__ W,
    const float* __restrict__ bias, float* __restrict__ C,
    const float* __restrict__ x, const float* __restrict__ h_steps,
    const float* __restrict__ tree_vec, const int* __restrict__ q_rows,
    const int* __restrict__ root_ids, const int* __restrict__ step_v){
  __shared__ float As[BM][BK+1], Ws[BK][BN+1];
  int bx = blockIdx.x, by = blockIdx.y;
  int tx = threadIdx.x & 15, ty = threadIdx.x >> 4;
  float acc[2][2] = {{0.f,0.f},{0.f,0.f}};
  for (int kt = 0; kt < K; kt += BK){
    for (int l = threadIdx.x; l < BM*BK; l += 256){
      int r = l / BK, c = l % BK;
      int gi = by*BM + r, gk = kt + c;
      float a = 0.f;
      if (gi < rows && gk < K){
        if (mode == 2){
          a = Aplain[(size_t)gi*K + gk];
        } else if (mode == 0){
          int row = q_rows[gi];
          int b = row % B_;
          if (gk < H_) a = (row < B_) ? 0.f : h_steps[(size_t)(row - B_)*H_ + gk];
          else         a = tree_vec[b*L_ + (gk - H_)];
        } else { // mode 1: p rows
          int i = gi; int b = i % B_;
          if (gk < H_){
            int xn = (i < B_) ? root_ids[b] : step_v[i - B_];
            a = x[(size_t)xn*H_ + gk];
          } else if (gk < 2*H_){
            a = (i < B_) ? 0.f : h_steps[(size_t)(i - B_)*H_ + (gk - H_)];
          } else {
            a = tree_vec[b*L_ + (gk - 2*H_)];
          }
        }
      }
      As[r][c] = a;
    }
    for (int l = threadIdx.x; l < BK*BN; l += 256){
      int r = l / BN, c = l % BN;
      int gk = kt + r, gc = bx*BN + c;
      Ws[r][c] = (gk < K && gc < cols) ? W[(size_t)gk*cols + gc] : 0.f;
    }
    __syncthreads();
    for (int kk = 0; kk < BK; ++kk){
      float a0 = As[ty*2][kk], a1 = As[ty*2+1][kk];
      float w0 = Ws[kk][tx*2], w1 = Ws[kk][tx*2+1];
      acc[0][0] += a0*w0; acc[0][1] += a0*w1;
      acc[1][0] += a1*w0; acc[1][1] += a1*w1;
    }
    __syncthreads();
  }
  for (int ii = 0; ii < 2; ++ii){
    int gi = by*BM + ty*2 + ii;
    if (gi >= rows) continue;
    for (int jj = 0; jj < 2; ++jj){
      int gc = bx*BN + tx*2 + jj;
      if (gc >= cols) continue;
      float v = acc[ii][jj] + bias[gc];
      if (act) v = fmaxf(v, 0.f);
      C[(size_t)gi*cols + gc] = v;
    }
  }
}

// Per-row: lse, argmax (first occurrence), target logit -> q_loss, q_acc
__global__ __launch_bounds__(256) void k_qreduce(const float* __restrict__ logits,
    const int* __restrict__ q_tgt, int nq, float* __restrict__ out){
  __shared__ float smax[256]; __shared__ int sidx[256]; __shared__ float ssum[256];
  int i = blockIdx.x;
  const float* lr = logits + (size_t)i*V_;
  float mx = -INFINITY; int mi = 0;
  for (int j = threadIdx.x; j < V_; j += 256){
    float v = lr[j];
    if (v > mx){ mx = v; mi = j; }
  }
  smax[threadIdx.x] = mx; sidx[threadIdx.x] = mi;
  __syncthreads();
  for (int s = 128; s > 0; s >>= 1){
    if (threadIdx.x < s){
      float v2 = smax[threadIdx.x+s]; int i2 = sidx[threadIdx.x+s];
      float v1 = smax[threadIdx.x];   int i1 = sidx[threadIdx.x];
      if (v2 > v1 || (v2 == v1 && i2 < i1)){ smax[threadIdx.x] = v2; sidx[threadIdx.x] = i2; }
    }
    __syncthreads();
  }
  float gmax = smax[0]; int gidx = sidx[0];
  float ps = 0.f;
  for (int j = threadIdx.x; j < V_; j += 256) ps += expf(lr[j]-gmax);
  ssum[threadIdx.x] = ps; __syncthreads();
  for (int s = 128; s > 0; s >>= 1){
    if (threadIdx.x < s) ssum[threadIdx.x] += ssum[threadIdx.x+s];
    __syncthreads();
  }
  if (threadIdx.x == 0){
    float lse = gmax + logf(ssum[0]);
    int tg = q_tgt[i];
    atomicAdd(out+0, (lse - lr[tg]) * (1.0f/B_));
    atomicAdd(out+2, (gidx == tg) ? (1.0f/(float)nq) : 0.f);
  }
}

// Per-row: p_logit = hidden.Us + bs -> BCE loss + acc
__global__ __launch_bounds__(256) void k_preduce(const float* __restrict__ hiddenp,
    const float* __restrict__ Us, const float* __restrict__ bs,
    const int* __restrict__ p_tgt, float* __restrict__ out){
  __shared__ float ssum[256];
  int i = blockIdx.x;
  const float* hr = hiddenp + (size_t)i*H_;
  float ps = 0.f;
  for (int j = threadIdx.x; j < H_; j += 256) ps += hr[j]*Us[j];
  ssum[threadIdx.x] = ps; __syncthreads();
  for (int s = 128; s > 0; s >>= 1){
    if (threadIdx.x < s) ssum[threadIdx.x] += ssum[threadIdx.x+s];
    __syncthreads();
  }
  if (threadIdx.x == 0){
    float pl = ssum[0] + bs[0];
    float tgt = (float)p_tgt[i];
    float loss = fmaxf(pl, 0.f) + log1pf(expf(-fabsf(pl))) - pl*tgt;
    atomicAdd(out+1, loss * (1.0f/B_));
    int pred = (pl > 0.f) ? 1 : 0;
    atomicAdd(out+3, (pred == p_tgt[i]) ? (1.0f/(float)NPROWS) : 0.f);
  }
}

extern "C" void kernel_launch(void* const* d_in, const int* in_sizes, int n_in,
                              void* d_out, int out_size, void* d_ws, size_t ws_size,
                              hipStream_t stream){
  const float* tree_vec = (const float*)d_in[0];
  const float* emb  = (const float*)d_in[1];
  const float* Wz   = (const float*)d_in[2];
  const float* bz   = (const float*)d_in[3];
  const float* Wh   = (const float*)d_in[4];
  const float* bh   = (const float*)d_in[5];
  const float* Wr   = (const float*)d_in[6];
  const float* Ur   = (const float*)d_in[7];
  const float* br   = (const float*)d_in[8];
  const float* Ww   = (const float*)d_in[9];
  const float* bw   = (const float*)d_in[10];
  const float* Uw   = (const float*)d_in[11];
  const float* bu   = (const float*)d_in[12];
  const float* Wo   = (const float*)d_in[13];
  const float* bo   = (const float*)d_in[14];
  const float* Us   = (const float*)d_in[15];
  const float* bs   = (const float*)d_in[16];
  const int* wid      = (const int*)d_in[17];
  const int* root_ids = (const int*)d_in[18];
  const int* edge_src = (const int*)d_in[19];
  const int* edge_dst = (const int*)d_in[20];
  const int* edge_pred= (const int*)d_in[21];
  const int* node_in  = (const int*)d_in[22];
  const int* step_eid = (const int*)d_in[23];
  const int* step_v   = (const int*)d_in[24];
  const int* q_rows   = (const int*)d_in[25];
  const int* q_tgt    = (const int*)d_in[26];
  const int* p_tgt    = (const int*)d_in[27];
  int P  = in_sizes[21] / NEDGES;
  int Dn = in_sizes[22] / NNODES;
  int nq = in_sizes[25];

  char* ws = (char*)d_ws;
  size_t off = 0;
  auto alloc = [&](size_t bytes){ void* p = ws + off; off += (bytes + 255) & ~255ull; return p; };
  float* x       = (float*)alloc((size_t)NNODES*H_*4);
  float* h_steps = (float*)alloc((size_t)T_*B_*H_*4);
  size_t Roff = off;
  float* m  = (float*)alloc((size_t)(NEDGES+1)*H_*4);
  float* rm = (float*)alloc((size_t)(NEDGES+1)*H_*4);
  float* A1 = (float*)alloc((size_t)B_*K2H*4);
  float* A2 = (float*)alloc((size_t)B_*K2H*4);
  float* A3 = (float*)alloc((size_t)B_*K2H*4);

  hipMemsetAsync(m,  0, (size_t)(NEDGES+1)*H_*4, stream);
  hipMemsetAsync(rm, 0, (size_t)(NEDGES+1)*H_*4, stream);
  hipMemsetAsync(d_out, 0, (size_t)out_size*sizeof(float), stream);

  k_gather_x<<<NNODES, 256, 0, stream>>>(emb, wid, x);

  dim3 gGate((H_+BN-1)/BN, (B_+BM-1)/BM);
  for (int t = 0; t < T_; ++t){
    k_prep<<<B_, 256, 0, stream>>>(x, m, rm, edge_src, edge_dst, edge_pred, step_eid, t, P, A1, A2, A3);
    k_gate<<<gGate, 256, 0, stream>>>(A1, A2, Wz, bz, Wh, bh, A3);
    k_rgate<<<gGate, 256, 0, stream>>>(A3, Wr, Ur, br, step_eid, t, m, rm);
    k_hpull<<<B_, 256, 0, stream>>>(m, node_in, step_v, t, Dn, h_steps);
  }

  // Final-phase buffers aliased over dead m/rm/A region
  float* hiddenq = (float*)(ws + Roff);
  float* logitsq = hiddenq + (size_t)nq*H_;
  // q hidden: [nq, 506] @ [506, 450], relu
  k_mm<<<dim3((H_+BN-1)/BN, (nq+BM-1)/BM), 256, 0, stream>>>(nq, H_, H_+L_, 0, 1,
      nullptr, Ww, bw, hiddenq, x, h_steps, tree_vec, q_rows, root_ids, step_v);
  // q logits: [nq, 450] @ [450, 780]
  k_mm<<<dim3((V_+BN-1)/BN, (nq+BM-1)/BM), 256, 0, stream>>>(nq, V_, H_, 2, 0,
      logitsq /*unused slot safety*/ == nullptr ? nullptr : hiddenq, Wo, bo, logitsq,
      x, h_steps, tree_vec, q_rows, root_ids, step_v);
  k_qreduce<<<nq, 256, 0, stream>>>(logitsq, q_tgt, nq, (float*)d_out);
  // p hidden: [19968, 956] @ [956, 450], relu  (reuses R region; q done)
  float* hiddenp = (float*)(ws + Roff);
  k_mm<<<dim3((H_+BN-1)/BN, (NPROWS+BM-1)/BM), 256, 0, stream>>>(NPROWS, H_, 2*H_+L_, 1, 1,
      nullptr, Uw, bu, hiddenp, x, h_steps, tree_vec, q_rows, root_ids, step_v);
  k_preduce<<<NPROWS, 256, 0, stream>>>(hiddenp, Us, bs, p_tgt, (float*)d_out);
}